// Round 12
// baseline (178.842 us; speedup 1.0000x reference)
//
#include <hip/hip_runtime.h>

// Problem constants (B=2, C=64, C8=8, H=W=96 -> N=9216)
#define NTOK  9216
#define NBAT  2

typedef __attribute__((ext_vector_type(8))) short bf16x8;
typedef __attribute__((ext_vector_type(4))) float f32x4;
typedef __attribute__((ext_vector_type(4))) unsigned int u32x4;
typedef __attribute__((ext_vector_type(2))) unsigned int u32x2;

#if __has_builtin(__builtin_amdgcn_exp2f)
#define EXP2(x) __builtin_amdgcn_exp2f(x)
#else
#define EXP2(x) exp2f(x)
#endif
#define L2E 1.4426950408889634f

__device__ __forceinline__ unsigned short f2bf(float x) {
  unsigned int u = __builtin_bit_cast(unsigned int, x);
  u += 0x7fffu + ((u >> 16) & 1u);   // RNE
  return (unsigned short)(u >> 16);
}

// pack two non-negative floats to bf16x2 (round-half-up via +0x8000, v_perm)
__device__ __forceinline__ unsigned int pack_bf2(float lo, float hi) {
  unsigned int ulo = __builtin_bit_cast(unsigned int, lo) + 0x8000u;
  unsigned int uhi = __builtin_bit_cast(unsigned int, hi) + 0x8000u;
  return __builtin_amdgcn_perm(uhi, ulo, 0x07060302u);
}

// gfx950 cross-row register swaps.
__device__ __forceinline__ void pl32(unsigned int &a, unsigned int &b) {
#if __has_builtin(__builtin_amdgcn_permlane32_swap)
  u32x2 r = __builtin_amdgcn_permlane32_swap(a, b, false, false);
  a = r[0]; b = r[1];
#else
  asm("v_permlane32_swap_b32 %0, %1" : "+v"(a), "+v"(b));
#endif
}
__device__ __forceinline__ void pl16(unsigned int &a, unsigned int &b) {
#if __has_builtin(__builtin_amdgcn_permlane16_swap)
  u32x2 r = __builtin_amdgcn_permlane16_swap(a, b, false, false);
  a = r[0]; b = r[1];
#else
  asm("v_permlane16_swap_b32 %0, %1" : "+v"(a), "+v"(b));
#endif
}

// ---------------------------------------------------------------------------
// Kernel 1: QKV projections -> bf16 (V in j-tiled layout). (r4 form)
// ---------------------------------------------------------------------------
__global__ __launch_bounds__(256) void qkv_proj(
    const float* __restrict__ x,
    const float* __restrict__ Wq, const float* __restrict__ bq,
    const float* __restrict__ Wk, const float* __restrict__ bk,
    const float* __restrict__ Wv, const float* __restrict__ bv,
    unsigned short* __restrict__ qg, unsigned short* __restrict__ kg,
    unsigned short* __restrict__ vg)
{
  __shared__ __align__(16) float xl[64 * 68];
  const int bid = blockIdx.x;
  const int rg  = bid % 5;
  const int t2  = bid / 5;
  const int nt  = t2 % 144;
  const int b   = t2 / 144;
  const int t   = threadIdx.x;
  const int lane = t & 63;
  const int n0  = nt * 64;

  #pragma unroll
  for (int kk = 0; kk < 4; kk++) {
    int p = t + kk * 256;
    int c = p >> 4, n4 = (p & 15) << 2;
    *(float4*)(&xl[c * 68 + n4]) =
        *(const float4*)(x + (size_t)(b * 64 + c) * NTOK + n0 + n4);
  }
  __syncthreads();

  const int g  = __builtin_amdgcn_readfirstlane(t >> 6);  // wave id 0..3
  const int r0 = rg * 16 + g * 4;                         // rows r0..r0+3 (0..79)

  const float* wbase; const float* bias_p; int lr0;
  if (r0 < 8)       { wbase = Wq; bias_p = bq; lr0 = r0; }
  else if (r0 < 16) { wbase = Wk; bias_p = bk; lr0 = r0 - 8; }
  else              { wbase = Wv; bias_p = bv; lr0 = r0 - 16; }
  const float* w0 = wbase + lr0 * 64;

  float a0 = 0.f, a1 = 0.f, a2 = 0.f, a3 = 0.f;
  #pragma unroll 16
  for (int c = 0; c < 64; c++) {
    float xv = xl[c * 68 + lane];
    a0 = fmaf(w0[c],       xv, a0);
    a1 = fmaf(w0[64 + c],  xv, a1);
    a2 = fmaf(w0[128 + c], xv, a2);
    a3 = fmaf(w0[192 + c], xv, a3);
  }
  a0 += bias_p[lr0]; a1 += bias_p[lr0 + 1];
  a2 += bias_p[lr0 + 2]; a3 += bias_p[lr0 + 3];
  if (r0 < 8) { a0 *= L2E; a1 *= L2E; a2 *= L2E; a3 *= L2E; }  // wave-uniform

  const int n = n0 + lane;
  if (r0 < 16) {
    ushort4 o;
    o.x = f2bf(a0); o.y = f2bf(a1); o.z = f2bf(a2); o.w = f2bf(a3);
    unsigned short* dst = (r0 < 8) ? qg : kg;
    *(ushort4*)(dst + ((size_t)b * NTOK + n) * 8 + lr0) = o;
  } else {
    // tiled V store: vt[(b*144 + nt)][c][lane], c = lr0..lr0+3
    unsigned short* vt = vg + ((size_t)(b * 144 + nt) * 64) * 64;
    vt[(lr0    ) * 64 + lane] = f2bf(a0);
    vt[(lr0 + 1) * 64 + lane] = f2bf(a1);
    vt[(lr0 + 2) * 64 + lane] = f2bf(a2);
    vt[(lr0 + 3) * 64 + lane] = f2bf(a3);
  }
}

// ---------------------------------------------------------------------------
// Kernel 2: flash partial, 64 q-rows x j-QUARTER, tuned to the 128-register
// occupancy step. Register ledger (m69-style: waves/SIMD step at unified
// 64/128/256): acc 64 + qf 16 + vf 16 + kf 8 + transients/addr ~24 = ~124
// <= 128 -> 4 waves/SIMD. Combines r10's reuse (fill term small) with r9's
// residency (stall term halved): 1152 blocks, 4 blocks/CU resident.
// launch_bounds(256,4) requests the 128 cap; body genuinely fits (unlike
// r2's forced fat body) -- FETCH/WRITE are the spill tripwire.
// ---------------------------------------------------------------------------
__global__ __launch_bounds__(256, 4) void flash_partial(
    const unsigned short* __restrict__ qg,
    const unsigned short* __restrict__ kg,
    const unsigned short* __restrict__ vg,
    float* __restrict__ opart, float* __restrict__ lpart)
{
  __shared__ __align__(16) float obuf[2 * 4224];  // 2 tiles [64ch][66] = 33792 B
  __shared__ float l_s[4][64];

  const int bid  = blockIdx.x;
  const int jq   = bid & 3;             // j-quarter
  const int t2   = bid >> 2;
  const int rt   = t2 % 144;            // 64-row q-tile index
  const int b    = t2 / 144;
  const int tid  = threadIdx.x;
  const int w    = tid >> 6;
  const int lane = tid & 63;
  const int i16  = lane & 15;
  const int quad = lane >> 4;
  const int jbase = jq * 2304 + (w << 6);  // 64-j slabs, stride 256 over waves

  const unsigned short* __restrict__ vb = vg + (size_t)b * 64 * NTOK; // tiled
  const unsigned short* __restrict__ kb = kg + (size_t)b * NTOK * 8;
  const int koff  = i16 * 8;
  const int vtoff = i16 * 64 + quad * 8;   // within a [c][64] j-tile slab

  bf16x8 qf[4] = {};
  if (quad == 0) {
    #pragma unroll
    for (int s = 0; s < 4; s++)
      qf[s] = *(const bf16x8*)(qg + ((size_t)b * NTOK + rt * 64 + s * 16 + i16) * 8);
  }

  f32x4 acc[4][4];
  #pragma unroll
  for (int s = 0; s < 4; s++)
    #pragma unroll
    for (int ct = 0; ct < 4; ct++) acc[s][ct] = (f32x4){0.f, 0.f, 0.f, 0.f};
  float lp[4] = {0.f, 0.f, 0.f, 0.f};
  const f32x4 z4 = {0.f, 0.f, 0.f, 0.f};

  #pragma unroll 1
  for (int it = 0; it < 18; ++it) {
    const int jp  = jbase + ((it >> 1) << 8);   // 64-aligned slab base
    const int jlo = (it & 1) << 5;              // 0 | 32 within slab

    bf16x8 kf[2];
    #pragma unroll
    for (int jt = 0; jt < 2; jt++)
      kf[jt] = *(const bf16x8*)(kb + (jp + jlo + jt * 16) * 8 + koff);
    bf16x8 vf[4];
    #pragma unroll
    for (int ct = 0; ct < 4; ct++)
      vf[ct] = *(const bf16x8*)(vb + (((size_t)(jp + ct * 16)) << 6) + vtoff + jlo);

    #pragma unroll
    for (int s = 0; s < 4; s++) {
      f32x4 st[2];
      #pragma unroll
      for (int jt = 0; jt < 2; jt++)
        st[jt] = __builtin_amdgcn_mfma_f32_16x16x32_bf16(kf[jt], qf[s], z4, 0, 0, 0);
      unsigned int pw[4];
      float ps = 0.f;
      #pragma unroll
      for (int jt = 0; jt < 2; jt++) {
        float p0 = EXP2(st[jt][0]);
        float p1 = EXP2(st[jt][1]);
        float p2 = EXP2(st[jt][2]);
        float p3 = EXP2(st[jt][3]);
        ps += (p0 + p1) + (p2 + p3);
        pw[jt * 2]     = pack_bf2(p0, p1);
        pw[jt * 2 + 1] = pack_bf2(p2, p3);
      }
      lp[s] += ps;

      unsigned int a0 = pw[0], a1 = pw[1];
      unsigned int b0 = pw[2], b1 = pw[3];
      pl32(a0, b0); pl16(a0, b0);   // a0 -> j=8q+{0,1}, b0 -> j=8q+{4,5}
      pl32(a1, b1); pl16(a1, b1);   // a1 -> j=8q+{2,3}, b1 -> j=8q+{6,7}
      u32x4 f = {a0, a1, b0, b1};
      bf16x8 pf = __builtin_bit_cast(bf16x8, f);
      #pragma unroll
      for (int ct = 0; ct < 4; ct++)
        acc[s][ct] = __builtin_amdgcn_mfma_f32_16x16x32_bf16(vf[ct], pf, acc[s][ct], 0, 0, 0);
    }
  }

  #pragma unroll
  for (int s = 0; s < 4; s++) {
    lp[s] += __shfl_xor(lp[s], 16);
    lp[s] += __shfl_xor(lp[s], 32);
  }
  if (quad == 0) {
    #pragma unroll
    for (int s = 0; s < 4; s++) l_s[w][s * 16 + i16] = lp[s];
  }

  // --- two-pass cross-wave reduction: only 2 tiles live in LDS at a time ---
  if (w >= 2) {
    float* dst = &obuf[(w - 2) * 4224];
    #pragma unroll
    for (int s = 0; s < 4; s++)
      #pragma unroll
      for (int ct = 0; ct < 4; ct++)
        #pragma unroll
        for (int r = 0; r < 4; r++)
          dst[(ct * 16 + quad * 4 + r) * 66 + s * 16 + i16] = acc[s][ct][r];
  }
  __syncthreads();
  if (w < 2) {
    float* t = &obuf[w * 4224];
    #pragma unroll
    for (int s = 0; s < 4; s++)
      #pragma unroll
      for (int ct = 0; ct < 4; ct++)
        #pragma unroll
        for (int r = 0; r < 4; r++) {
          int idx = (ct * 16 + quad * 4 + r) * 66 + s * 16 + i16;
          t[idx] += acc[s][ct][r];   // per-lane read-modify-write, bijective
        }
  }
  __syncthreads();

  float* ob = opart + (size_t)bid * 4096;   // [64ch][64row]
  #pragma unroll
  for (int e0 = 0; e0 < 16; e0++) {
    int e = tid + e0 * 256, c = e >> 6, r = e & 63;
    ob[e] = obuf[c * 66 + r] + obuf[4224 + c * 66 + r];
  }
  if (tid < 64)
    lpart[(size_t)bid * 64 + tid] =
        (l_s[0][tid] + l_s[1][tid]) + (l_s[2][tid] + l_s[3][tid]);
}

// ---------------------------------------------------------------------------
// Kernel 3: merge the 4 j-quarter partials + epilogue: y = gs*O/L + x.
// 288 blocks, one per 64-row q-tile.
// ---------------------------------------------------------------------------
__global__ __launch_bounds__(256) void reduce_ep(
    const float* __restrict__ x,
    const float* __restrict__ opart, const float* __restrict__ lpart,
    const float* __restrict__ gamma_p, const float* __restrict__ dyn_p,
    float* __restrict__ y)
{
  const int bid = blockIdx.x;            // b*144 + rt
  const int b = bid / 144, rt = bid % 144;
  const int tid = threadIdx.x;
  const float gs = gamma_p[0] * dyn_p[0];
  const float* o0 = opart + (size_t)(bid * 4) * 4096;
  const float* l0 = lpart + (size_t)(bid * 4) * 64;
  #pragma unroll
  for (int e0 = 0; e0 < 16; e0++) {
    int e = tid + e0 * 256, c = e >> 6, r = e & 63;
    float L = (l0[r] + l0[64 + r]) + (l0[128 + r] + l0[192 + r]);
    float O = (o0[e] + o0[4096 + e]) + (o0[8192 + e] + o0[12288 + e]);
    size_t a = (size_t)(b * 64 + c) * NTOK + rt * 64 + r;
    y[a] = gs * O / L + x[a];
  }
}

// ---------------------------------------------------------------------------
extern "C" void kernel_launch(void* const* d_in, const int* in_sizes, int n_in,
                              void* d_out, int out_size, void* d_ws, size_t ws_size,
                              hipStream_t stream) {
  const float* x     = (const float*)d_in[0];
  const float* Wq    = (const float*)d_in[1];
  const float* bq    = (const float*)d_in[2];
  const float* Wk    = (const float*)d_in[3];
  const float* bk    = (const float*)d_in[4];
  const float* Wv    = (const float*)d_in[5];
  const float* bv    = (const float*)d_in[6];
  const float* gamma = (const float*)d_in[7];
  const float* dyn   = (const float*)d_in[8];
  float* y = (float*)d_out;

  // workspace layout (bf16 then f32, 16B-aligned boundaries); ~22.1 MB total
  unsigned short* qg = (unsigned short*)d_ws;              // B*N*8
  unsigned short* kg = qg + (size_t)NBAT * NTOK * 8;       // B*N*8
  unsigned short* vg = kg + (size_t)NBAT * NTOK * 8;       // B*64*N (tiled)
  float* opart = (float*)(vg + (size_t)NBAT * 64 * NTOK);  // 1152*4096 f32
  float* lpart = opart + (size_t)1152 * 4096;              // 1152*64   f32

  qkv_proj<<<NBAT * 144 * 5, 256, 0, stream>>>(x, Wq, bq, Wk, bk, Wv, bv, qg, kg, vg);
  flash_partial<<<NBAT * 144 * 4, 256, 0, stream>>>(qg, kg, vg, opart, lpart);
  reduce_ep<<<NBAT * 144, 256, 0, stream>>>(x, opart, lpart, gamma, dyn, y);
}

// Round 13
// 147.818 us; speedup vs baseline: 1.2099x; 1.2099x over previous
//
#include <hip/hip_runtime.h>

// Problem constants (B=2, C=64, C8=8, H=W=96 -> N=9216)
#define NTOK  9216
#define NBAT  2

typedef __attribute__((ext_vector_type(8))) short bf16x8;
typedef __attribute__((ext_vector_type(4))) float f32x4;
typedef __attribute__((ext_vector_type(4))) unsigned int u32x4;
typedef __attribute__((ext_vector_type(2))) unsigned int u32x2;

#if __has_builtin(__builtin_amdgcn_exp2f)
#define EXP2(x) __builtin_amdgcn_exp2f(x)
#else
#define EXP2(x) exp2f(x)
#endif
#define L2E 1.4426950408889634f

__device__ __forceinline__ unsigned short f2bf(float x) {
  unsigned int u = __builtin_bit_cast(unsigned int, x);
  u += 0x7fffu + ((u >> 16) & 1u);   // RNE
  return (unsigned short)(u >> 16);
}

// pack two non-negative floats to bf16x2 (round-half-up via +0x8000, v_perm)
__device__ __forceinline__ unsigned int pack_bf2(float lo, float hi) {
  unsigned int ulo = __builtin_bit_cast(unsigned int, lo) + 0x8000u;
  unsigned int uhi = __builtin_bit_cast(unsigned int, hi) + 0x8000u;
  return __builtin_amdgcn_perm(uhi, ulo, 0x07060302u);
}

// gfx950 cross-row register swaps.
__device__ __forceinline__ void pl32(unsigned int &a, unsigned int &b) {
#if __has_builtin(__builtin_amdgcn_permlane32_swap)
  u32x2 r = __builtin_amdgcn_permlane32_swap(a, b, false, false);
  a = r[0]; b = r[1];
#else
  asm("v_permlane32_swap_b32 %0, %1" : "+v"(a), "+v"(b));
#endif
}
__device__ __forceinline__ void pl16(unsigned int &a, unsigned int &b) {
#if __has_builtin(__builtin_amdgcn_permlane16_swap)
  u32x2 r = __builtin_amdgcn_permlane16_swap(a, b, false, false);
  a = r[0]; b = r[1];
#else
  asm("v_permlane16_swap_b32 %0, %1" : "+v"(a), "+v"(b));
#endif
}

// ---------------------------------------------------------------------------
// Kernel 1: QKV projections -> bf16 (V in j-tiled layout). (r4 form)
// ---------------------------------------------------------------------------
__global__ __launch_bounds__(256) void qkv_proj(
    const float* __restrict__ x,
    const float* __restrict__ Wq, const float* __restrict__ bq,
    const float* __restrict__ Wk, const float* __restrict__ bk,
    const float* __restrict__ Wv, const float* __restrict__ bv,
    unsigned short* __restrict__ qg, unsigned short* __restrict__ kg,
    unsigned short* __restrict__ vg)
{
  __shared__ __align__(16) float xl[64 * 68];
  const int bid = blockIdx.x;
  const int rg  = bid % 5;
  const int t2  = bid / 5;
  const int nt  = t2 % 144;
  const int b   = t2 / 144;
  const int t   = threadIdx.x;
  const int lane = t & 63;
  const int n0  = nt * 64;

  #pragma unroll
  for (int kk = 0; kk < 4; kk++) {
    int p = t + kk * 256;
    int c = p >> 4, n4 = (p & 15) << 2;
    *(float4*)(&xl[c * 68 + n4]) =
        *(const float4*)(x + (size_t)(b * 64 + c) * NTOK + n0 + n4);
  }
  __syncthreads();

  const int g  = __builtin_amdgcn_readfirstlane(t >> 6);  // wave id 0..3
  const int r0 = rg * 16 + g * 4;                         // rows r0..r0+3 (0..79)

  const float* wbase; const float* bias_p; int lr0;
  if (r0 < 8)       { wbase = Wq; bias_p = bq; lr0 = r0; }
  else if (r0 < 16) { wbase = Wk; bias_p = bk; lr0 = r0 - 8; }
  else              { wbase = Wv; bias_p = bv; lr0 = r0 - 16; }
  const float* w0 = wbase + lr0 * 64;

  float a0 = 0.f, a1 = 0.f, a2 = 0.f, a3 = 0.f;
  #pragma unroll 16
  for (int c = 0; c < 64; c++) {
    float xv = xl[c * 68 + lane];
    a0 = fmaf(w0[c],       xv, a0);
    a1 = fmaf(w0[64 + c],  xv, a1);
    a2 = fmaf(w0[128 + c], xv, a2);
    a3 = fmaf(w0[192 + c], xv, a3);
  }
  a0 += bias_p[lr0]; a1 += bias_p[lr0 + 1];
  a2 += bias_p[lr0 + 2]; a3 += bias_p[lr0 + 3];
  if (r0 < 8) { a0 *= L2E; a1 *= L2E; a2 *= L2E; a3 *= L2E; }  // wave-uniform

  const int n = n0 + lane;
  if (r0 < 16) {
    ushort4 o;
    o.x = f2bf(a0); o.y = f2bf(a1); o.z = f2bf(a2); o.w = f2bf(a3);
    unsigned short* dst = (r0 < 8) ? qg : kg;
    *(ushort4*)(dst + ((size_t)b * NTOK + n) * 8 + lr0) = o;
  } else {
    // tiled V store: vt[(b*144 + nt)][c][lane], c = lr0..lr0+3
    unsigned short* vt = vg + ((size_t)(b * 144 + nt) * 64) * 64;
    vt[(lr0    ) * 64 + lane] = f2bf(a0);
    vt[(lr0 + 1) * 64 + lane] = f2bf(a1);
    vt[(lr0 + 2) * 64 + lane] = f2bf(a2);
    vt[(lr0 + 3) * 64 + lane] = f2bf(a3);
  }
}

// ---------------------------------------------------------------------------
// Kernel 2: flash partial with LDS-SHARED K/V slabs. Block = 256 q-rows x
// j-eighth (1152 j). The 4 waves partition Q (64 rows each, acc[4][4]) and
// all compute against the SAME 64-j slab staged in double-buffered LDS
// (V 8KB XOR-swizzled + K 1KB = 9216 B/buf). This breaks the register
// ceiling on reuse: total V traffic = 85 MB (r11: 170, r9: 680) -> fill
// term ~9us, and waves own disjoint q-rows -> NO cross-wave LDS merge.
// Staging is reg-staged (issue loads one slab ahead; write after barrier);
// 2 barriers/iter. 576 blocks @ ~2/CU.
// ---------------------------------------------------------------------------
__global__ __launch_bounds__(256, 2) void flash_partial(
    const unsigned short* __restrict__ qg,
    const unsigned short* __restrict__ kg,
    const unsigned short* __restrict__ vg,
    float* __restrict__ opart, float* __restrict__ lpart)
{
  __shared__ __align__(16) unsigned short lds[2 * 4608];  // 18432 B

  const int bid  = blockIdx.x;
  const int js   = bid & 7;             // j-eighth
  const int t2   = bid >> 3;
  const int tile = t2 % 36;             // 256-row q-tile
  const int b    = t2 / 36;
  const int tid  = threadIdx.x;
  const int w    = tid >> 6;
  const int lane = tid & 63;
  const int i16  = lane & 15;
  const int quad = lane >> 4;

  const unsigned short* __restrict__ vb = vg + (size_t)b * 64 * NTOK; // tiled
  const unsigned short* __restrict__ kb = kg + (size_t)b * NTOK * 8;
  const int slab0 = js * 18;            // 18 slabs of 64 j per block
  char* ldsb = (char*)lds;

  // V staging write offsets (swizzled: byte_in_row ^= (ch&7)<<4), c = 0,1
  int vwb[2];
  #pragma unroll
  for (int c = 0; c < 2; c++) {
    int E  = c * 2048 + tid * 8;        // element offset in [64ch][64j] slab
    int ch = E >> 6;
    int j2 = (E & 63) * 2;              // byte-in-row (multiple of 16)
    vwb[c] = ch * 128 + (j2 ^ ((ch & 7) << 4));
  }

  bf16x8 qf[4] = {};
  if (quad == 0) {
    #pragma unroll
    for (int s = 0; s < 4; s++)
      qf[s] = *(const bf16x8*)(qg +
          ((size_t)b * NTOK + tile * 256 + w * 64 + s * 16 + i16) * 8);
  }

  f32x4 acc[4][4];
  #pragma unroll
  for (int s = 0; s < 4; s++)
    #pragma unroll
    for (int ct = 0; ct < 4; ct++) acc[s][ct] = (f32x4){0.f, 0.f, 0.f, 0.f};
  float lp[4] = {0.f, 0.f, 0.f, 0.f};
  const f32x4 z4 = {0.f, 0.f, 0.f, 0.f};

  // --- prologue: stage slab0 into buf0; issue loads for slab1 ---
  bf16x8 gv0, gv1, gk = {};
  gv0 = *(const bf16x8*)(vb + (size_t)slab0 * 4096 + tid * 8);
  gv1 = *(const bf16x8*)(vb + (size_t)slab0 * 4096 + 2048 + tid * 8);
  if (w == 0) gk = *(const bf16x8*)(kb + ((size_t)(slab0 * 64 + lane)) * 8);
  *(bf16x8*)(ldsb + vwb[0]) = gv0;
  *(bf16x8*)(ldsb + vwb[1]) = gv1;
  if (w == 0) *(bf16x8*)(ldsb + 8192 + lane * 16) = gk;
  gv0 = *(const bf16x8*)(vb + (size_t)(slab0 + 1) * 4096 + tid * 8);
  gv1 = *(const bf16x8*)(vb + (size_t)(slab0 + 1) * 4096 + 2048 + tid * 8);
  if (w == 0) gk = *(const bf16x8*)(kb + ((size_t)((slab0 + 1) * 64 + lane)) * 8);
  __syncthreads();

  #pragma unroll 1
  for (int it = 0; it < 18; ++it) {
    char* bufc = ldsb + (it & 1) * 9216;
    if (it > 0) __syncthreads();        // everyone done reading buf[(it+1)&1]
    if (it < 17) {
      char* bufn = ldsb + ((it + 1) & 1) * 9216;
      *(bf16x8*)(bufn + vwb[0]) = gv0;  // vmcnt wait auto-inserted
      *(bf16x8*)(bufn + vwb[1]) = gv1;
      if (w == 0) *(bf16x8*)(bufn + 8192 + lane * 16) = gk;
      if (it < 16) {
        const int sl = slab0 + it + 2;  // loads land during compute(it)+
        gv0 = *(const bf16x8*)(vb + (size_t)sl * 4096 + tid * 8);
        gv1 = *(const bf16x8*)(vb + (size_t)sl * 4096 + 2048 + tid * 8);
        if (w == 0) gk = *(const bf16x8*)(kb + ((size_t)(sl * 64 + lane)) * 8);
      }
    }
    __syncthreads();                    // buf[it&1] complete for all waves

    #pragma unroll
    for (int jh = 0; jh < 2; ++jh) {    // two 32-j halves of the slab
      bf16x8 kf[2];
      #pragma unroll
      for (int jt = 0; jt < 2; jt++)
        kf[jt] = *(const bf16x8*)(bufc + 8192 + (jh * 32 + jt * 16 + i16) * 16);
      bf16x8 vf[4];
      #pragma unroll
      for (int ct = 0; ct < 4; ct++)
        vf[ct] = *(const bf16x8*)(bufc + (ct * 16 + i16) * 128 +
                                  ((jh * 64 + quad * 16) ^ ((i16 & 7) << 4)));
      #pragma unroll
      for (int s = 0; s < 4; s++) {
        f32x4 st[2];
        #pragma unroll
        for (int jt = 0; jt < 2; jt++)
          st[jt] = __builtin_amdgcn_mfma_f32_16x16x32_bf16(kf[jt], qf[s], z4, 0, 0, 0);
        unsigned int pw[4];
        float ps = 0.f;
        #pragma unroll
        for (int jt = 0; jt < 2; jt++) {
          float p0 = EXP2(st[jt][0]);
          float p1 = EXP2(st[jt][1]);
          float p2 = EXP2(st[jt][2]);
          float p3 = EXP2(st[jt][3]);
          ps += (p0 + p1) + (p2 + p3);
          pw[jt * 2]     = pack_bf2(p0, p1);
          pw[jt * 2 + 1] = pack_bf2(p2, p3);
        }
        lp[s] += ps;

        unsigned int a0 = pw[0], a1 = pw[1];
        unsigned int b0 = pw[2], b1 = pw[3];
        pl32(a0, b0); pl16(a0, b0);   // a0 -> j=8q+{0,1}, b0 -> j=8q+{4,5}
        pl32(a1, b1); pl16(a1, b1);   // a1 -> j=8q+{2,3}, b1 -> j=8q+{6,7}
        u32x4 f = {a0, a1, b0, b1};
        bf16x8 pf = __builtin_bit_cast(bf16x8, f);
        #pragma unroll
        for (int ct = 0; ct < 4; ct++)
          acc[s][ct] = __builtin_amdgcn_mfma_f32_16x16x32_bf16(vf[ct], pf, acc[s][ct], 0, 0, 0);
      }
    }
  }

  #pragma unroll
  for (int s = 0; s < 4; s++) {
    lp[s] += __shfl_xor(lp[s], 16);
    lp[s] += __shfl_xor(lp[s], 32);
  }

  // --- direct epilogue: waves own disjoint q-rows -> no cross-wave merge ---
  float* ob = opart + (size_t)bid * 16384;   // [64ch][256q]
  #pragma unroll
  for (int s = 0; s < 4; s++)
    #pragma unroll
    for (int ct = 0; ct < 4; ct++)
      #pragma unroll
      for (int r = 0; r < 4; r++)
        ob[(ct * 16 + quad * 4 + r) * 256 + w * 64 + s * 16 + i16] = acc[s][ct][r];
  if (quad == 0) {
    #pragma unroll
    for (int s = 0; s < 4; s++)
      lpart[(size_t)bid * 256 + w * 64 + s * 16 + i16] = lp[s];
  }
}

// ---------------------------------------------------------------------------
// Kernel 3: merge the 8 j-eighth partials + epilogue: y = gs*O/L + x.
// 288 blocks; each handles a 64-row quarter of a 256-row q-tile.
// ---------------------------------------------------------------------------
__global__ __launch_bounds__(256) void reduce_ep(
    const float* __restrict__ x,
    const float* __restrict__ opart, const float* __restrict__ lpart,
    const float* __restrict__ gamma_p, const float* __restrict__ dyn_p,
    float* __restrict__ y)
{
  const int bid = blockIdx.x;            // (b*36 + tile)*4 + sub
  const int sub = bid & 3;
  const int t   = bid >> 2;
  const int tile = t % 36, b = t / 36;
  const int tid = threadIdx.x;
  const float gs = gamma_p[0] * dyn_p[0];
  const float* o0 = opart + (size_t)t * 8 * 16384;
  const float* l0 = lpart + (size_t)t * 8 * 256;
  #pragma unroll 1
  for (int e0 = 0; e0 < 16; e0++) {
    int e = tid + e0 * 256;              // 0..4095 = [64ch][64row]
    int c = e >> 6, rr = e & 63;
    int q = sub * 64 + rr;
    float L = 0.f, O = 0.f;
    #pragma unroll
    for (int jsp = 0; jsp < 8; jsp++) {
      L += l0[jsp * 256 + q];
      O += o0[(size_t)jsp * 16384 + c * 256 + q];
    }
    size_t a = (size_t)(b * 64 + c) * NTOK + tile * 256 + q;
    y[a] = gs * O / L + x[a];
  }
}

// ---------------------------------------------------------------------------
extern "C" void kernel_launch(void* const* d_in, const int* in_sizes, int n_in,
                              void* d_out, int out_size, void* d_ws, size_t ws_size,
                              hipStream_t stream) {
  const float* x     = (const float*)d_in[0];
  const float* Wq    = (const float*)d_in[1];
  const float* bq    = (const float*)d_in[2];
  const float* Wk    = (const float*)d_in[3];
  const float* bk    = (const float*)d_in[4];
  const float* Wv    = (const float*)d_in[5];
  const float* bv    = (const float*)d_in[6];
  const float* gamma = (const float*)d_in[7];
  const float* dyn   = (const float*)d_in[8];
  float* y = (float*)d_out;

  // workspace layout (bf16 then f32, 16B-aligned boundaries); ~41.3 MB total
  unsigned short* qg = (unsigned short*)d_ws;              // B*N*8
  unsigned short* kg = qg + (size_t)NBAT * NTOK * 8;       // B*N*8
  unsigned short* vg = kg + (size_t)NBAT * NTOK * 8;       // B*64*N (tiled)
  float* opart = (float*)(vg + (size_t)NBAT * 64 * NTOK);  // 576*16384 f32
  float* lpart = opart + (size_t)576 * 16384;              // 576*256   f32

  qkv_proj<<<NBAT * 144 * 5, 256, 0, stream>>>(x, Wq, bq, Wk, bk, Wv, bv, qg, kg, vg);
  flash_partial<<<NBAT * 36 * 8, 256, 0, stream>>>(qg, kg, vg, opart, lpart);
  reduce_ep<<<NBAT * 36 * 4, 256, 0, stream>>>(x, opart, lpart, gamma, dyn, y);
}

// Round 14
// 138.768 us; speedup vs baseline: 1.2888x; 1.0652x over previous
//
#include <hip/hip_runtime.h>

// Problem constants (B=2, C=64, C8=8, H=W=96 -> N=9216)
#define NTOK  9216
#define NBAT  2

typedef __attribute__((ext_vector_type(8))) short bf16x8;
typedef __attribute__((ext_vector_type(4))) float f32x4;
typedef __attribute__((ext_vector_type(4))) unsigned int u32x4;
typedef __attribute__((ext_vector_type(2))) unsigned int u32x2;

#if __has_builtin(__builtin_amdgcn_exp2f)
#define EXP2(x) __builtin_amdgcn_exp2f(x)
#else
#define EXP2(x) exp2f(x)
#endif
#define L2E 1.4426950408889634f

__device__ __forceinline__ unsigned short f2bf(float x) {
  unsigned int u = __builtin_bit_cast(unsigned int, x);
  u += 0x7fffu + ((u >> 16) & 1u);   // RNE
  return (unsigned short)(u >> 16);
}

// pack two non-negative floats to bf16x2 (round-half-up via +0x8000, v_perm)
__device__ __forceinline__ unsigned int pack_bf2(float lo, float hi) {
  unsigned int ulo = __builtin_bit_cast(unsigned int, lo) + 0x8000u;
  unsigned int uhi = __builtin_bit_cast(unsigned int, hi) + 0x8000u;
  return __builtin_amdgcn_perm(uhi, ulo, 0x07060302u);
}

// gfx950 cross-row register swaps.
__device__ __forceinline__ void pl32(unsigned int &a, unsigned int &b) {
#if __has_builtin(__builtin_amdgcn_permlane32_swap)
  u32x2 r = __builtin_amdgcn_permlane32_swap(a, b, false, false);
  a = r[0]; b = r[1];
#else
  asm("v_permlane32_swap_b32 %0, %1" : "+v"(a), "+v"(b));
#endif
}
__device__ __forceinline__ void pl16(unsigned int &a, unsigned int &b) {
#if __has_builtin(__builtin_amdgcn_permlane16_swap)
  u32x2 r = __builtin_amdgcn_permlane16_swap(a, b, false, false);
  a = r[0]; b = r[1];
#else
  asm("v_permlane16_swap_b32 %0, %1" : "+v"(a), "+v"(b));
#endif
}

// ---------------------------------------------------------------------------
// Kernel 1: QKV projections -> bf16 (V in j-tiled layout). (r4 form)
// ---------------------------------------------------------------------------
__global__ __launch_bounds__(256) void qkv_proj(
    const float* __restrict__ x,
    const float* __restrict__ Wq, const float* __restrict__ bq,
    const float* __restrict__ Wk, const float* __restrict__ bk,
    const float* __restrict__ Wv, const float* __restrict__ bv,
    unsigned short* __restrict__ qg, unsigned short* __restrict__ kg,
    unsigned short* __restrict__ vg)
{
  __shared__ __align__(16) float xl[64 * 68];
  const int bid = blockIdx.x;
  const int rg  = bid % 5;
  const int t2  = bid / 5;
  const int nt  = t2 % 144;
  const int b   = t2 / 144;
  const int t   = threadIdx.x;
  const int lane = t & 63;
  const int n0  = nt * 64;

  #pragma unroll
  for (int kk = 0; kk < 4; kk++) {
    int p = t + kk * 256;
    int c = p >> 4, n4 = (p & 15) << 2;
    *(float4*)(&xl[c * 68 + n4]) =
        *(const float4*)(x + (size_t)(b * 64 + c) * NTOK + n0 + n4);
  }
  __syncthreads();

  const int g  = __builtin_amdgcn_readfirstlane(t >> 6);  // wave id 0..3
  const int r0 = rg * 16 + g * 4;                         // rows r0..r0+3 (0..79)

  const float* wbase; const float* bias_p; int lr0;
  if (r0 < 8)       { wbase = Wq; bias_p = bq; lr0 = r0; }
  else if (r0 < 16) { wbase = Wk; bias_p = bk; lr0 = r0 - 8; }
  else              { wbase = Wv; bias_p = bv; lr0 = r0 - 16; }
  const float* w0 = wbase + lr0 * 64;

  float a0 = 0.f, a1 = 0.f, a2 = 0.f, a3 = 0.f;
  #pragma unroll 16
  for (int c = 0; c < 64; c++) {
    float xv = xl[c * 68 + lane];
    a0 = fmaf(w0[c],       xv, a0);
    a1 = fmaf(w0[64 + c],  xv, a1);
    a2 = fmaf(w0[128 + c], xv, a2);
    a3 = fmaf(w0[192 + c], xv, a3);
  }
  a0 += bias_p[lr0]; a1 += bias_p[lr0 + 1];
  a2 += bias_p[lr0 + 2]; a3 += bias_p[lr0 + 3];
  if (r0 < 8) { a0 *= L2E; a1 *= L2E; a2 *= L2E; a3 *= L2E; }  // wave-uniform

  const int n = n0 + lane;
  if (r0 < 16) {
    ushort4 o;
    o.x = f2bf(a0); o.y = f2bf(a1); o.z = f2bf(a2); o.w = f2bf(a3);
    unsigned short* dst = (r0 < 8) ? qg : kg;
    *(ushort4*)(dst + ((size_t)b * NTOK + n) * 8 + lr0) = o;
  } else {
    // tiled V store: vt[(b*144 + nt)][c][lane], c = lr0..lr0+3
    unsigned short* vt = vg + ((size_t)(b * 144 + nt) * 64) * 64;
    vt[(lr0    ) * 64 + lane] = f2bf(a0);
    vt[(lr0 + 1) * 64 + lane] = f2bf(a1);
    vt[(lr0 + 2) * 64 + lane] = f2bf(a2);
    vt[(lr0 + 3) * 64 + lane] = f2bf(a3);
  }
}

// ---------------------------------------------------------------------------
// Kernel 2: flash partial, LDS-shared K/V slabs (r13 structure) SIZED TO THE
// 128-UNIFIED-REGISTER BUCKET. Block = 128 q-rows x j-eighth; each wave owns
// 32 q-rows (acc[2][4] = 32 regs; unified ~110 <= 128 -> 4 waves/SIMD,
// 4 blocks/CU). r13 ran at ~1 wave/SIMD so every barrier/staging wait was
// fully exposed; here 3 co-resident blocks cover them. Staging, swizzle and
// sync structure byte-identical to r13 (single-variable test of TLP at low
// V traffic: 85 MB total, far below the fill-saturation knee).
// ---------------------------------------------------------------------------
__global__ __launch_bounds__(256, 4) void flash_partial(
    const unsigned short* __restrict__ qg,
    const unsigned short* __restrict__ kg,
    const unsigned short* __restrict__ vg,
    float* __restrict__ opart, float* __restrict__ lpart)
{
  __shared__ __align__(16) unsigned short lds[2 * 4608];  // 18432 B

  const int bid  = blockIdx.x;
  const int js   = bid & 7;             // j-eighth
  const int t2   = bid >> 3;
  const int tile = t2 % 72;             // 128-row q-tile
  const int b    = t2 / 72;
  const int tid  = threadIdx.x;
  const int w    = tid >> 6;
  const int lane = tid & 63;
  const int i16  = lane & 15;
  const int quad = lane >> 4;

  const unsigned short* __restrict__ vb = vg + (size_t)b * 64 * NTOK; // tiled
  const unsigned short* __restrict__ kb = kg + (size_t)b * NTOK * 8;
  const int slab0 = js * 18;            // 18 slabs of 64 j per block
  char* ldsb = (char*)lds;

  // V staging write offsets (swizzled: byte_in_row ^= (ch&7)<<4), c = 0,1
  int vwb[2];
  #pragma unroll
  for (int c = 0; c < 2; c++) {
    int E  = c * 2048 + tid * 8;        // element offset in [64ch][64j] slab
    int ch = E >> 6;
    int j2 = (E & 63) * 2;              // byte-in-row (multiple of 16)
    vwb[c] = ch * 128 + (j2 ^ ((ch & 7) << 4));
  }

  bf16x8 qf[2] = {};
  if (quad == 0) {
    #pragma unroll
    for (int s = 0; s < 2; s++)
      qf[s] = *(const bf16x8*)(qg +
          ((size_t)b * NTOK + tile * 128 + w * 32 + s * 16 + i16) * 8);
  }

  f32x4 acc[2][4];
  #pragma unroll
  for (int s = 0; s < 2; s++)
    #pragma unroll
    for (int ct = 0; ct < 4; ct++) acc[s][ct] = (f32x4){0.f, 0.f, 0.f, 0.f};
  float lp[2] = {0.f, 0.f};
  const f32x4 z4 = {0.f, 0.f, 0.f, 0.f};

  // --- prologue: stage slab0 into buf0; issue loads for slab1 ---
  bf16x8 gv0, gv1, gk = {};
  gv0 = *(const bf16x8*)(vb + (size_t)slab0 * 4096 + tid * 8);
  gv1 = *(const bf16x8*)(vb + (size_t)slab0 * 4096 + 2048 + tid * 8);
  if (w == 0) gk = *(const bf16x8*)(kb + ((size_t)(slab0 * 64 + lane)) * 8);
  *(bf16x8*)(ldsb + vwb[0]) = gv0;
  *(bf16x8*)(ldsb + vwb[1]) = gv1;
  if (w == 0) *(bf16x8*)(ldsb + 8192 + lane * 16) = gk;
  gv0 = *(const bf16x8*)(vb + (size_t)(slab0 + 1) * 4096 + tid * 8);
  gv1 = *(const bf16x8*)(vb + (size_t)(slab0 + 1) * 4096 + 2048 + tid * 8);
  if (w == 0) gk = *(const bf16x8*)(kb + ((size_t)((slab0 + 1) * 64 + lane)) * 8);
  __syncthreads();

  #pragma unroll 1
  for (int it = 0; it < 18; ++it) {
    char* bufc = ldsb + (it & 1) * 9216;
    if (it > 0) __syncthreads();        // everyone done reading buf[(it+1)&1]
    if (it < 17) {
      char* bufn = ldsb + ((it + 1) & 1) * 9216;
      *(bf16x8*)(bufn + vwb[0]) = gv0;  // vmcnt wait auto-inserted
      *(bf16x8*)(bufn + vwb[1]) = gv1;
      if (w == 0) *(bf16x8*)(bufn + 8192 + lane * 16) = gk;
      if (it < 16) {
        const int sl = slab0 + it + 2;  // loads land during compute(it)+
        gv0 = *(const bf16x8*)(vb + (size_t)sl * 4096 + tid * 8);
        gv1 = *(const bf16x8*)(vb + (size_t)sl * 4096 + 2048 + tid * 8);
        if (w == 0) gk = *(const bf16x8*)(kb + ((size_t)(sl * 64 + lane)) * 8);
      }
    }
    __syncthreads();                    // buf[it&1] complete for all waves

    #pragma unroll
    for (int jh = 0; jh < 2; ++jh) {    // two 32-j halves of the slab
      bf16x8 kf[2];
      #pragma unroll
      for (int jt = 0; jt < 2; jt++)
        kf[jt] = *(const bf16x8*)(bufc + 8192 + (jh * 32 + jt * 16 + i16) * 16);
      bf16x8 vf[4];
      #pragma unroll
      for (int ct = 0; ct < 4; ct++)
        vf[ct] = *(const bf16x8*)(bufc + (ct * 16 + i16) * 128 +
                                  ((jh * 64 + quad * 16) ^ ((i16 & 7) << 4)));
      #pragma unroll
      for (int s = 0; s < 2; s++) {
        f32x4 st[2];
        #pragma unroll
        for (int jt = 0; jt < 2; jt++)
          st[jt] = __builtin_amdgcn_mfma_f32_16x16x32_bf16(kf[jt], qf[s], z4, 0, 0, 0);
        unsigned int pw[4];
        float ps = 0.f;
        #pragma unroll
        for (int jt = 0; jt < 2; jt++) {
          float p0 = EXP2(st[jt][0]);
          float p1 = EXP2(st[jt][1]);
          float p2 = EXP2(st[jt][2]);
          float p3 = EXP2(st[jt][3]);
          ps += (p0 + p1) + (p2 + p3);
          pw[jt * 2]     = pack_bf2(p0, p1);
          pw[jt * 2 + 1] = pack_bf2(p2, p3);
        }
        lp[s] += ps;

        unsigned int a0 = pw[0], a1 = pw[1];
        unsigned int b0 = pw[2], b1 = pw[3];
        pl32(a0, b0); pl16(a0, b0);   // a0 -> j=8q+{0,1}, b0 -> j=8q+{4,5}
        pl32(a1, b1); pl16(a1, b1);   // a1 -> j=8q+{2,3}, b1 -> j=8q+{6,7}
        u32x4 f = {a0, a1, b0, b1};
        bf16x8 pf = __builtin_bit_cast(bf16x8, f);
        #pragma unroll
        for (int ct = 0; ct < 4; ct++)
          acc[s][ct] = __builtin_amdgcn_mfma_f32_16x16x32_bf16(vf[ct], pf, acc[s][ct], 0, 0, 0);
      }
    }
  }

  #pragma unroll
  for (int s = 0; s < 2; s++) {
    lp[s] += __shfl_xor(lp[s], 16);
    lp[s] += __shfl_xor(lp[s], 32);
  }

  // --- direct epilogue: waves own disjoint q-rows -> no cross-wave merge ---
  float* ob = opart + (size_t)bid * 8192;   // [64ch][128q]
  #pragma unroll
  for (int s = 0; s < 2; s++)
    #pragma unroll
    for (int ct = 0; ct < 4; ct++)
      #pragma unroll
      for (int r = 0; r < 4; r++)
        ob[(ct * 16 + quad * 4 + r) * 128 + w * 32 + s * 16 + i16] = acc[s][ct][r];
  if (quad == 0) {
    #pragma unroll
    for (int s = 0; s < 2; s++)
      lpart[(size_t)bid * 128 + w * 32 + s * 16 + i16] = lp[s];
  }
}

// ---------------------------------------------------------------------------
// Kernel 3: merge the 8 j-eighth partials + epilogue: y = gs*O/L + x.
// 288 blocks; each handles a 64-row half of a 128-row q-tile.
// ---------------------------------------------------------------------------
__global__ __launch_bounds__(256) void reduce_ep(
    const float* __restrict__ x,
    const float* __restrict__ opart, const float* __restrict__ lpart,
    const float* __restrict__ gamma_p, const float* __restrict__ dyn_p,
    float* __restrict__ y)
{
  const int bid = blockIdx.x;            // (b*72 + tile)*2 + h
  const int h   = bid & 1;
  const int t   = bid >> 1;
  const int tile = t % 72, b = t / 72;
  const int tid = threadIdx.x;
  const float gs = gamma_p[0] * dyn_p[0];
  const float* o0 = opart + (size_t)t * 8 * 8192;
  const float* l0 = lpart + (size_t)t * 8 * 128;
  #pragma unroll 1
  for (int e0 = 0; e0 < 16; e0++) {
    int e = tid + e0 * 256;              // 0..4095 = [64ch][64row]
    int c = e >> 6, rr = e & 63;
    int q = h * 64 + rr;
    float L = 0.f, O = 0.f;
    #pragma unroll
    for (int jsp = 0; jsp < 8; jsp++) {
      L += l0[jsp * 128 + q];
      O += o0[(size_t)jsp * 8192 + c * 128 + q];
    }
    size_t a = (size_t)(b * 64 + c) * NTOK + tile * 128 + q;
    y[a] = gs * O / L + x[a];
  }
}

// ---------------------------------------------------------------------------
extern "C" void kernel_launch(void* const* d_in, const int* in_sizes, int n_in,
                              void* d_out, int out_size, void* d_ws, size_t ws_size,
                              hipStream_t stream) {
  const float* x     = (const float*)d_in[0];
  const float* Wq    = (const float*)d_in[1];
  const float* bq    = (const float*)d_in[2];
  const float* Wk    = (const float*)d_in[3];
  const float* bk    = (const float*)d_in[4];
  const float* Wv    = (const float*)d_in[5];
  const float* bv    = (const float*)d_in[6];
  const float* gamma = (const float*)d_in[7];
  const float* dyn   = (const float*)d_in[8];
  float* y = (float*)d_out;

  // workspace layout (bf16 then f32, 16B-aligned boundaries); ~41 MB total
  unsigned short* qg = (unsigned short*)d_ws;              // B*N*8
  unsigned short* kg = qg + (size_t)NBAT * NTOK * 8;       // B*N*8
  unsigned short* vg = kg + (size_t)NBAT * NTOK * 8;       // B*64*N (tiled)
  float* opart = (float*)(vg + (size_t)NBAT * 64 * NTOK);  // 1152*8192 f32
  float* lpart = opart + (size_t)1152 * 8192;              // 1152*128  f32

  qkv_proj<<<NBAT * 144 * 5, 256, 0, stream>>>(x, Wq, bq, Wk, bk, Wv, bv, qg, kg, vg);
  flash_partial<<<NBAT * 72 * 8, 256, 0, stream>>>(qg, kg, vg, opart, lpart);
  reduce_ep<<<NBAT * 72 * 2, 256, 0, stream>>>(x, opart, lpart, gamma, dyn, y);
}

// Round 15
// 133.419 us; speedup vs baseline: 1.3404x; 1.0401x over previous
//
#include <hip/hip_runtime.h>

// Problem constants (B=2, C=64, C8=8, H=W=96 -> N=9216)
#define NTOK  9216
#define NBAT  2

typedef __attribute__((ext_vector_type(8))) short bf16x8;
typedef __attribute__((ext_vector_type(4))) float f32x4;
typedef __attribute__((ext_vector_type(4))) unsigned int u32x4;
typedef __attribute__((ext_vector_type(2))) unsigned int u32x2;

#if __has_builtin(__builtin_amdgcn_exp2f)
#define EXP2(x) __builtin_amdgcn_exp2f(x)
#else
#define EXP2(x) exp2f(x)
#endif
#define L2E 1.4426950408889634f

__device__ __forceinline__ unsigned short f2bf(float x) {
  unsigned int u = __builtin_bit_cast(unsigned int, x);
  u += 0x7fffu + ((u >> 16) & 1u);   // RNE
  return (unsigned short)(u >> 16);
}

// pack two floats to bf16x2 in ONE VALU op (r15: was 2x v_add + v_perm).
// low16 = bf16(lo), high16 = bf16(hi) -- same placement as the old perm.
__device__ __forceinline__ unsigned int pack_bf2(float lo, float hi) {
  unsigned int r;
  asm("v_cvt_pk_bf16_f32 %0, %1, %2" : "=v"(r) : "v"(lo), "v"(hi));
  return r;
}

// gfx950 cross-row register swaps.
__device__ __forceinline__ void pl32(unsigned int &a, unsigned int &b) {
#if __has_builtin(__builtin_amdgcn_permlane32_swap)
  u32x2 r = __builtin_amdgcn_permlane32_swap(a, b, false, false);
  a = r[0]; b = r[1];
#else
  asm("v_permlane32_swap_b32 %0, %1" : "+v"(a), "+v"(b));
#endif
}
__device__ __forceinline__ void pl16(unsigned int &a, unsigned int &b) {
#if __has_builtin(__builtin_amdgcn_permlane16_swap)
  u32x2 r = __builtin_amdgcn_permlane16_swap(a, b, false, false);
  a = r[0]; b = r[1];
#else
  asm("v_permlane16_swap_b32 %0, %1" : "+v"(a), "+v"(b));
#endif
}

// ---------------------------------------------------------------------------
// Kernel 1: QKV projections -> bf16 (V in j-tiled layout). (r4 form)
// ---------------------------------------------------------------------------
__global__ __launch_bounds__(256) void qkv_proj(
    const float* __restrict__ x,
    const float* __restrict__ Wq, const float* __restrict__ bq,
    const float* __restrict__ Wk, const float* __restrict__ bk,
    const float* __restrict__ Wv, const float* __restrict__ bv,
    unsigned short* __restrict__ qg, unsigned short* __restrict__ kg,
    unsigned short* __restrict__ vg)
{
  __shared__ __align__(16) float xl[64 * 68];
  const int bid = blockIdx.x;
  const int rg  = bid % 5;
  const int t2  = bid / 5;
  const int nt  = t2 % 144;
  const int b   = t2 / 144;
  const int t   = threadIdx.x;
  const int lane = t & 63;
  const int n0  = nt * 64;

  #pragma unroll
  for (int kk = 0; kk < 4; kk++) {
    int p = t + kk * 256;
    int c = p >> 4, n4 = (p & 15) << 2;
    *(float4*)(&xl[c * 68 + n4]) =
        *(const float4*)(x + (size_t)(b * 64 + c) * NTOK + n0 + n4);
  }
  __syncthreads();

  const int g  = __builtin_amdgcn_readfirstlane(t >> 6);  // wave id 0..3
  const int r0 = rg * 16 + g * 4;                         // rows r0..r0+3 (0..79)

  const float* wbase; const float* bias_p; int lr0;
  if (r0 < 8)       { wbase = Wq; bias_p = bq; lr0 = r0; }
  else if (r0 < 16) { wbase = Wk; bias_p = bk; lr0 = r0 - 8; }
  else              { wbase = Wv; bias_p = bv; lr0 = r0 - 16; }
  const float* w0 = wbase + lr0 * 64;

  float a0 = 0.f, a1 = 0.f, a2 = 0.f, a3 = 0.f;
  #pragma unroll 16
  for (int c = 0; c < 64; c++) {
    float xv = xl[c * 68 + lane];
    a0 = fmaf(w0[c],       xv, a0);
    a1 = fmaf(w0[64 + c],  xv, a1);
    a2 = fmaf(w0[128 + c], xv, a2);
    a3 = fmaf(w0[192 + c], xv, a3);
  }
  a0 += bias_p[lr0]; a1 += bias_p[lr0 + 1];
  a2 += bias_p[lr0 + 2]; a3 += bias_p[lr0 + 3];
  if (r0 < 8) { a0 *= L2E; a1 *= L2E; a2 *= L2E; a3 *= L2E; }  // wave-uniform

  const int n = n0 + lane;
  if (r0 < 16) {
    ushort4 o;
    o.x = f2bf(a0); o.y = f2bf(a1); o.z = f2bf(a2); o.w = f2bf(a3);
    unsigned short* dst = (r0 < 8) ? qg : kg;
    *(ushort4*)(dst + ((size_t)b * NTOK + n) * 8 + lr0) = o;
  } else {
    // tiled V store: vt[(b*144 + nt)][c][lane], c = lr0..lr0+3
    unsigned short* vt = vg + ((size_t)(b * 144 + nt) * 64) * 64;
    vt[(lr0    ) * 64 + lane] = f2bf(a0);
    vt[(lr0 + 1) * 64 + lane] = f2bf(a1);
    vt[(lr0 + 2) * 64 + lane] = f2bf(a2);
    vt[(lr0 + 3) * 64 + lane] = f2bf(a3);
  }
}

// ---------------------------------------------------------------------------
// Kernel 2: flash partial, LDS-shared K/V slabs, 128-register bucket (r14).
// r15 (VALU-issue cut; structure frozen): (1) pack_bf2 = v_cvt_pk_bf16_f32
// (1 op, was 3) -- r14 showed VALUBusy 49.6% vs MfmaUtil 22%, softmax VALU
// chain is the issue bottleneck; (2) s_setprio(1) around MFMA clusters
// (T5 regime: independent multi-block waves + staging role-split).
// ---------------------------------------------------------------------------
__global__ __launch_bounds__(256, 4) void flash_partial(
    const unsigned short* __restrict__ qg,
    const unsigned short* __restrict__ kg,
    const unsigned short* __restrict__ vg,
    float* __restrict__ opart, float* __restrict__ lpart)
{
  __shared__ __align__(16) unsigned short lds[2 * 4608];  // 18432 B

  const int bid  = blockIdx.x;
  const int js   = bid & 7;             // j-eighth
  const int t2   = bid >> 3;
  const int tile = t2 % 72;             // 128-row q-tile
  const int b    = t2 / 72;
  const int tid  = threadIdx.x;
  const int w    = tid >> 6;
  const int lane = tid & 63;
  const int i16  = lane & 15;
  const int quad = lane >> 4;

  const unsigned short* __restrict__ vb = vg + (size_t)b * 64 * NTOK; // tiled
  const unsigned short* __restrict__ kb = kg + (size_t)b * NTOK * 8;
  const int slab0 = js * 18;            // 18 slabs of 64 j per block
  char* ldsb = (char*)lds;

  // V staging write offsets (swizzled: byte_in_row ^= (ch&7)<<4), c = 0,1
  int vwb[2];
  #pragma unroll
  for (int c = 0; c < 2; c++) {
    int E  = c * 2048 + tid * 8;        // element offset in [64ch][64j] slab
    int ch = E >> 6;
    int j2 = (E & 63) * 2;              // byte-in-row (multiple of 16)
    vwb[c] = ch * 128 + (j2 ^ ((ch & 7) << 4));
  }

  bf16x8 qf[2] = {};
  if (quad == 0) {
    #pragma unroll
    for (int s = 0; s < 2; s++)
      qf[s] = *(const bf16x8*)(qg +
          ((size_t)b * NTOK + tile * 128 + w * 32 + s * 16 + i16) * 8);
  }

  f32x4 acc[2][4];
  #pragma unroll
  for (int s = 0; s < 2; s++)
    #pragma unroll
    for (int ct = 0; ct < 4; ct++) acc[s][ct] = (f32x4){0.f, 0.f, 0.f, 0.f};
  float lp[2] = {0.f, 0.f};
  const f32x4 z4 = {0.f, 0.f, 0.f, 0.f};

  // --- prologue: stage slab0 into buf0; issue loads for slab1 ---
  bf16x8 gv0, gv1, gk = {};
  gv0 = *(const bf16x8*)(vb + (size_t)slab0 * 4096 + tid * 8);
  gv1 = *(const bf16x8*)(vb + (size_t)slab0 * 4096 + 2048 + tid * 8);
  if (w == 0) gk = *(const bf16x8*)(kb + ((size_t)(slab0 * 64 + lane)) * 8);
  *(bf16x8*)(ldsb + vwb[0]) = gv0;
  *(bf16x8*)(ldsb + vwb[1]) = gv1;
  if (w == 0) *(bf16x8*)(ldsb + 8192 + lane * 16) = gk;
  gv0 = *(const bf16x8*)(vb + (size_t)(slab0 + 1) * 4096 + tid * 8);
  gv1 = *(const bf16x8*)(vb + (size_t)(slab0 + 1) * 4096 + 2048 + tid * 8);
  if (w == 0) gk = *(const bf16x8*)(kb + ((size_t)((slab0 + 1) * 64 + lane)) * 8);
  __syncthreads();

  #pragma unroll 1
  for (int it = 0; it < 18; ++it) {
    char* bufc = ldsb + (it & 1) * 9216;
    if (it > 0) __syncthreads();        // everyone done reading buf[(it+1)&1]
    if (it < 17) {
      char* bufn = ldsb + ((it + 1) & 1) * 9216;
      *(bf16x8*)(bufn + vwb[0]) = gv0;  // vmcnt wait auto-inserted
      *(bf16x8*)(bufn + vwb[1]) = gv1;
      if (w == 0) *(bf16x8*)(bufn + 8192 + lane * 16) = gk;
      if (it < 16) {
        const int sl = slab0 + it + 2;  // loads land during compute(it)+
        gv0 = *(const bf16x8*)(vb + (size_t)sl * 4096 + tid * 8);
        gv1 = *(const bf16x8*)(vb + (size_t)sl * 4096 + 2048 + tid * 8);
        if (w == 0) gk = *(const bf16x8*)(kb + ((size_t)(sl * 64 + lane)) * 8);
      }
    }
    __syncthreads();                    // buf[it&1] complete for all waves

    #pragma unroll
    for (int jh = 0; jh < 2; ++jh) {    // two 32-j halves of the slab
      bf16x8 kf[2];
      #pragma unroll
      for (int jt = 0; jt < 2; jt++)
        kf[jt] = *(const bf16x8*)(bufc + 8192 + (jh * 32 + jt * 16 + i16) * 16);
      bf16x8 vf[4];
      #pragma unroll
      for (int ct = 0; ct < 4; ct++)
        vf[ct] = *(const bf16x8*)(bufc + (ct * 16 + i16) * 128 +
                                  ((jh * 64 + quad * 16) ^ ((i16 & 7) << 4)));
      #pragma unroll
      for (int s = 0; s < 2; s++) {
        f32x4 st[2];
        __builtin_amdgcn_s_setprio(1);
        #pragma unroll
        for (int jt = 0; jt < 2; jt++)
          st[jt] = __builtin_amdgcn_mfma_f32_16x16x32_bf16(kf[jt], qf[s], z4, 0, 0, 0);
        __builtin_amdgcn_s_setprio(0);
        unsigned int pw[4];
        float ps = 0.f;
        #pragma unroll
        for (int jt = 0; jt < 2; jt++) {
          float p0 = EXP2(st[jt][0]);
          float p1 = EXP2(st[jt][1]);
          float p2 = EXP2(st[jt][2]);
          float p3 = EXP2(st[jt][3]);
          ps += (p0 + p1) + (p2 + p3);
          pw[jt * 2]     = pack_bf2(p0, p1);
          pw[jt * 2 + 1] = pack_bf2(p2, p3);
        }
        lp[s] += ps;

        unsigned int a0 = pw[0], a1 = pw[1];
        unsigned int b0 = pw[2], b1 = pw[3];
        pl32(a0, b0); pl16(a0, b0);   // a0 -> j=8q+{0,1}, b0 -> j=8q+{4,5}
        pl32(a1, b1); pl16(a1, b1);   // a1 -> j=8q+{2,3}, b1 -> j=8q+{6,7}
        u32x4 f = {a0, a1, b0, b1};
        bf16x8 pf = __builtin_bit_cast(bf16x8, f);
        __builtin_amdgcn_s_setprio(1);
        #pragma unroll
        for (int ct = 0; ct < 4; ct++)
          acc[s][ct] = __builtin_amdgcn_mfma_f32_16x16x32_bf16(vf[ct], pf, acc[s][ct], 0, 0, 0);
        __builtin_amdgcn_s_setprio(0);
      }
    }
  }

  #pragma unroll
  for (int s = 0; s < 2; s++) {
    lp[s] += __shfl_xor(lp[s], 16);
    lp[s] += __shfl_xor(lp[s], 32);
  }

  // --- direct epilogue: waves own disjoint q-rows -> no cross-wave merge ---
  float* ob = opart + (size_t)bid * 8192;   // [64ch][128q]
  #pragma unroll
  for (int s = 0; s < 2; s++)
    #pragma unroll
    for (int ct = 0; ct < 4; ct++)
      #pragma unroll
      for (int r = 0; r < 4; r++)
        ob[(ct * 16 + quad * 4 + r) * 128 + w * 32 + s * 16 + i16] = acc[s][ct][r];
  if (quad == 0) {
    #pragma unroll
    for (int s = 0; s < 2; s++)
      lpart[(size_t)bid * 128 + w * 32 + s * 16 + i16] = lp[s];
  }
}

// ---------------------------------------------------------------------------
// Kernel 3: merge the 8 j-eighth partials + epilogue: y = gs*O/L + x.
// 288 blocks; each handles a 64-row half of a 128-row q-tile.
// ---------------------------------------------------------------------------
__global__ __launch_bounds__(256) void reduce_ep(
    const float* __restrict__ x,
    const float* __restrict__ opart, const float* __restrict__ lpart,
    const float* __restrict__ gamma_p, const float* __restrict__ dyn_p,
    float* __restrict__ y)
{
  const int bid = blockIdx.x;            // (b*72 + tile)*2 + h
  const int h   = bid & 1;
  const int t   = bid >> 1;
  const int tile = t % 72, b = t / 72;
  const int tid = threadIdx.x;
  const float gs = gamma_p[0] * dyn_p[0];
  const float* o0 = opart + (size_t)t * 8 * 8192;
  const float* l0 = lpart + (size_t)t * 8 * 128;
  #pragma unroll 1
  for (int e0 = 0; e0 < 16; e0++) {
    int e = tid + e0 * 256;              // 0..4095 = [64ch][64row]
    int c = e >> 6, rr = e & 63;
    int q = h * 64 + rr;
    float L = 0.f, O = 0.f;
    #pragma unroll
    for (int jsp = 0; jsp < 8; jsp++) {
      L += l0[jsp * 128 + q];
      O += o0[(size_t)jsp * 8192 + c * 128 + q];
    }
    size_t a = (size_t)(b * 64 + c) * NTOK + tile * 128 + q;
    y[a] = gs * O / L + x[a];
  }
}

// ---------------------------------------------------------------------------
extern "C" void kernel_launch(void* const* d_in, const int* in_sizes, int n_in,
                              void* d_out, int out_size, void* d_ws, size_t ws_size,
                              hipStream_t stream) {
  const float* x     = (const float*)d_in[0];
  const float* Wq    = (const float*)d_in[1];
  const float* bq    = (const float*)d_in[2];
  const float* Wk    = (const float*)d_in[3];
  const float* bk    = (const float*)d_in[4];
  const float* Wv    = (const float*)d_in[5];
  const float* bv    = (const float*)d_in[6];
  const float* gamma = (const float*)d_in[7];
  const float* dyn   = (const float*)d_in[8];
  float* y = (float*)d_out;

  // workspace layout (bf16 then f32, 16B-aligned boundaries); ~41 MB total
  unsigned short* qg = (unsigned short*)d_ws;              // B*N*8
  unsigned short* kg = qg + (size_t)NBAT * NTOK * 8;       // B*N*8
  unsigned short* vg = kg + (size_t)NBAT * NTOK * 8;       // B*64*N (tiled)
  float* opart = (float*)(vg + (size_t)NBAT * 64 * NTOK);  // 1152*8192 f32
  float* lpart = opart + (size_t)1152 * 8192;              // 1152*128  f32

  qkv_proj<<<NBAT * 144 * 5, 256, 0, stream>>>(x, Wq, bq, Wk, bk, Wv, bv, qg, kg, vg);
  flash_partial<<<NBAT * 72 * 8, 256, 0, stream>>>(qg, kg, vg, opart, lpart);
  reduce_ep<<<NBAT * 72 * 2, 256, 0, stream>>>(x, opart, lpart, gamma, dyn, y);
}